// Round 7
// baseline (246.618 us; speedup 1.0000x reference)
//
#include <hip/hip_runtime.h>
#include <hip/hip_fp16.h>
#include <math.h>

#define N_ENT 100000
#define N_REL 64
#define DIM   128
#define KNB   32
#define BATCH 16384
#define STRIPS (N_ENT / 16)   // 6250

typedef _Float16 f16;
typedef __attribute__((ext_vector_type(2))) _Float16 f16x2;
typedef __attribute__((ext_vector_type(8))) _Float16 f16x8;
typedef __attribute__((ext_vector_type(4))) float floatx4;

__device__ __forceinline__ int clamp_id(int id) {
    return id < 0 ? 0 : (id > N_ENT - 1 ? N_ENT - 1 : id);
}

__device__ __forceinline__ f16x2 h2v(__half2 h) {
    union { __half2 h; f16x2 v; } u; u.h = h; return u.v;
}
__device__ __forceinline__ __half2 u2h(unsigned int x) {
    union { unsigned int u; __half2 h; } c; c.u = x; return c.h;
}

// ---------------------------------------------------------------------------
// Kernel S (merged small prep):
//  blocks 0..63:  f16 copies of Wr/W1/W2 (row-major = MFMA B layout)
//  blocks 64..79: REL16 = f16(maxnorm(rel_table)), one wave per row
// ---------------------------------------------------------------------------
__global__ __launch_bounds__(256) void k_small(
    const float* __restrict__ Wr, const float* __restrict__ W1,
    const float* __restrict__ W2, f16* __restrict__ Wr16,
    f16* __restrict__ W116, f16* __restrict__ W216,
    const float* __restrict__ rel, __half2* __restrict__ REL2)
{
    if (blockIdx.x < 64) {
        const int t = blockIdx.x * 256 + threadIdx.x;   // 0..16383
        Wr16[t] = (f16)Wr[t];
        W116[t] = (f16)W1[t];
        W216[t] = (f16)W2[t];
    } else {
        const int lane = threadIdx.x & 63;
        const int row  = (blockIdx.x - 64) * 4 + (threadIdx.x >> 6);
        const float2 x = *(const float2*)(rel + row * DIM + 2 * lane);
        float ss = x.x * x.x + x.y * x.y;
        #pragma unroll
        for (int m = 1; m < 64; m <<= 1) ss += __shfl_xor(ss, m);
        const float s = fminf(1.0f, 1.0f / fmaxf(sqrtf(ss), 1e-12f));
        REL2[row * 64 + lane] = __floats2half2_rn(x.x * s, x.y * s);
    }
}

// ---------------------------------------------------------------------------
// Kernel P v3: fused maxnorm + GEMM, writing the INTERLEAVED NT table:
//   NT row (512B) = 64 pairs of {N.half2 (4B), TR.half2 (4B)} per col-pair.
// One dwordx2 gather in k_sag then fetches both the score operand (TR) and
// the aggregate operand (N) -> 64 gathers/wave becomes 32.
//  - Wr staged to LDS once per block in MFMA-fragment order (conflict-free).
//  - 2 strips per wave; 16 ent loads issued up-front.
// ---------------------------------------------------------------------------
__global__ __launch_bounds__(256, 4) void k_pre(
    const float* __restrict__ ent, const f16* __restrict__ B,
    const float* __restrict__ bias, char* __restrict__ ntb)
{
    __shared__ f16 Bs[32 * 512];   // 32 slots x 1024B = 32 KB
    const int wid  = threadIdx.x >> 6;
    const int lane = threadIdx.x & 63;
    const int m = lane & 15, quad = lane >> 4;

    // stage B into LDS in fragment order (8 slots per wave)
    #pragma unroll
    for (int i = 0; i < 8; ++i) {
        const int s  = wid * 8 + i;
        const int ct = s >> 2, kt = s & 3;
        const f16* gsrc = B + (size_t)(ct * 16 + m) * DIM + kt * 32 + quad * 8;
        __builtin_amdgcn_global_load_lds(
            (const __attribute__((address_space(1))) unsigned int*)gsrc,
            (__attribute__((address_space(3))) unsigned int*)(Bs + s * 512),
            16, 0, 0);
    }

    // two strips per wave; clamp => redundant but bitwise-identical writes
    const int wstrip = (blockIdx.x * 4 + wid) * 2;
    const int s0 = wstrip     < STRIPS ? wstrip     : STRIPS - 1;
    const int s1 = wstrip + 1 < STRIPS ? wstrip + 1 : STRIPS - 1;

    const float* __restrict__ src0 = ent + (size_t)(s0 * 16 + m) * DIM + quad * 8;
    const float* __restrict__ src1 = ent + (size_t)(s1 * 16 + m) * DIM + quad * 8;
    float x0[4][8], x1[4][8];
    #pragma unroll
    for (int kt = 0; kt < 4; ++kt) {
        *(float4*)&x0[kt][0] = *(const float4*)(src0 + kt * 32);
        *(float4*)&x0[kt][4] = *(const float4*)(src0 + kt * 32 + 4);
    }
    #pragma unroll
    for (int kt = 0; kt < 4; ++kt) {
        *(float4*)&x1[kt][0] = *(const float4*)(src1 + kt * 32);
        *(float4*)&x1[kt][4] = *(const float4*)(src1 + kt * 32 + 4);
    }
    __builtin_amdgcn_sched_barrier(0);   // all 16 loads + staging stay issued here

    // strip 0: norm -> a-frags -> N halves of NT
    float ss0 = 0.0f;
    #pragma unroll
    for (int kt = 0; kt < 4; ++kt)
        #pragma unroll
        for (int j = 0; j < 8; ++j) ss0 = fmaf(x0[kt][j], x0[kt][j], ss0);
    ss0 += __shfl_xor(ss0, 16);
    ss0 += __shfl_xor(ss0, 32);
    const float sc0 = fminf(1.0f, 1.0f / fmaxf(sqrtf(ss0), 1e-12f));
    f16x8 a0[4];
    {
        char* nrow = ntb + (size_t)(s0 * 16 + m) * 512;
        #pragma unroll
        for (int kt = 0; kt < 4; ++kt) {
            f16x8 av;
            #pragma unroll
            for (int j = 0; j < 8; ++j) av[j] = (f16)(x0[kt][j] * sc0);
            a0[kt] = av;
            #pragma unroll
            for (int p = 0; p < 4; ++p) {
                union { f16x2 v; __half2 h; } c;
                c.v = (f16x2){av[2 * p], av[2 * p + 1]};
                // pair index c2 = kt*16 + quad*4 + p; N half at +0
                *(__half2*)(nrow + (size_t)(kt * 16 + quad * 4 + p) * 8) = c.h;
            }
        }
    }

    // strip 1
    float ss1 = 0.0f;
    #pragma unroll
    for (int kt = 0; kt < 4; ++kt)
        #pragma unroll
        for (int j = 0; j < 8; ++j) ss1 = fmaf(x1[kt][j], x1[kt][j], ss1);
    ss1 += __shfl_xor(ss1, 16);
    ss1 += __shfl_xor(ss1, 32);
    const float sc1 = fminf(1.0f, 1.0f / fmaxf(sqrtf(ss1), 1e-12f));
    f16x8 a1[4];
    {
        char* nrow = ntb + (size_t)(s1 * 16 + m) * 512;
        #pragma unroll
        for (int kt = 0; kt < 4; ++kt) {
            f16x8 av;
            #pragma unroll
            for (int j = 0; j < 8; ++j) av[j] = (f16)(x1[kt][j] * sc1);
            a1[kt] = av;
            #pragma unroll
            for (int p = 0; p < 4; ++p) {
                union { f16x2 v; __half2 h; } c;
                c.v = (f16x2){av[2 * p], av[2 * p + 1]};
                *(__half2*)(nrow + (size_t)(kt * 16 + quad * 4 + p) * 8) = c.h;
            }
        }
    }

    __syncthreads();   // staging complete (drains vmcnt), LDS visible

    // MFMA: 8 col-tiles x 4 k-tiles; TR halves of NT (byte +4 in each pair)
    #pragma unroll
    for (int ct = 0; ct < 8; ++ct) {
        floatx4 acc0 = {0.0f, 0.0f, 0.0f, 0.0f};
        floatx4 acc1 = {0.0f, 0.0f, 0.0f, 0.0f};
        #pragma unroll
        for (int kt = 0; kt < 4; ++kt) {
            const f16x8 b = *(const f16x8*)(Bs + (ct * 4 + kt) * 512 + lane * 8);
            acc0 = __builtin_amdgcn_mfma_f32_16x16x32_f16(a0[kt], b, acc0, 0, 0, 0);
            acc1 = __builtin_amdgcn_mfma_f32_16x16x32_f16(a1[kt], b, acc1, 0, 0, 0);
        }
        const float bb = bias[ct * 16 + m];
        // col = ct*16+m -> pair c2 = ct*8 + (m>>1), .x/.y by m&1
        const size_t coff = (size_t)(ct * 8 + (m >> 1)) * 8 + 4 + (m & 1) * 2;
        #pragma unroll
        for (int r = 0; r < 4; ++r) {
            char* trow = ntb + (size_t)(s0 * 16 + quad * 4 + r) * 512;
            *(f16*)(trow + coff) = (f16)(acc0[r] + bb);
            char* trow1 = ntb + (size_t)(s1 * 16 + quad * 4 + r) * 512;
            *(f16*)(trow1 + coff) = (f16)(acc1[r] + bb);
        }
    }
}

// ---------------------------------------------------------------------------
// Kernel SG v4 (merged k_sa + k_gemm_out): one block = 16 batch rows,
// 16 waves (1024 threads), one element per wave -- the R5 structure (best
// measured: 45.6us; R6's 512-thread split regressed to 51us via doubled
// per-block epilogue overhead).
// NEW: gathers hit the interleaved NT table -- ONE dwordx2 per k fetches
// both TR (score) and N (aggregate) -> 32 gathers/wave instead of 64, half
// the outstanding-request pressure (the diagnosed latency limiter: VALU 42%,
// HBM 38%, nothing saturated).
// ---------------------------------------------------------------------------
__global__ __launch_bounds__(1024, 8) void k_sag(
    const int* __restrict__ idx, const int* __restrict__ adj_ent,
    const int* __restrict__ adj_rel, const char* __restrict__ nt,
    const __half2* __restrict__ REL2,
    const f16* __restrict__ W1h, const float* __restrict__ b1,
    const f16* __restrict__ W2h, const float* __restrict__ b2,
    float* __restrict__ out)
{
    __shared__ f16 Us[16 * DIM];   // 4 KB, 16B-chunk XOR swizzle by row
    __shared__ f16 Vs[16 * DIM];   // 4 KB
    const int wid  = threadIdx.x >> 6;   // 0..15 = element / LDS row
    const int lane = threadIdx.x & 63;
    const int row0 = blockIdx.x * 16;

    const __half2 C1 = __float2half2_rn(-0.33333334f);
    const __half2 C2 = __float2half2_rn(0.13333334f);

    {
        const int r = wid;
        const int b = row0 + r;
        const int id = clamp_id(idx[b]);
        // self row: one dwordx2 gives {N(id), TR(id)}
        const uint2 pr0 = *(const uint2*)(nt + (size_t)id * 512 + lane * 8);
        const float2 h  = __half22float2(u2h(pr0.x));
        const __half2 hr2 = u2h(pr0.y);
        const int eL = adj_ent[(size_t)id * KNB + (lane & 31)];
        const int rL = adj_rel[(size_t)id * KNB + (lane & 31)];

        // phase 1: one NT gather per k -> tr for score, n saved for phase 3
        unsigned int nds[KNB];
        float p[KNB];
        #pragma unroll
        for (int k = 0; k < KNB; ++k) {
            const int e  = __builtin_amdgcn_readlane(eL, k);
            const int rr = __builtin_amdgcn_readlane(rL, k);
            const uint2 pr = *(const uint2*)(nt + (size_t)e * 512 + lane * 8);
            nds[k] = pr.x;
            const __half2 tr2 = u2h(pr.y);
            const __half2 rn2 = REL2[rr * 64 + lane];
            const __half2 x  = __hadd2(hr2, rn2);
            const __half2 xx = __hmul2(x, x);
            __half2 q = __hfma2(xx, C2, C1);     // c1 + c2*x2
            q = __hmul2(q, xx);                  // x2*(c1 + c2*x2)
            const __half2 mm = __hfma2(x, q, x); // tanh(x) approx
#if __has_builtin(__builtin_amdgcn_fdot2)
            p[k] = __builtin_amdgcn_fdot2(h2v(mm), h2v(tr2), 0.0f, false);
#else
            const float2 mf = __half22float2(mm);
            const float2 tf = __half22float2(tr2);
            p[k] = mf.x * tf.x + mf.y * tf.y;
#endif
        }

        // transpose-reduce tree: all 32 lane-sums at once
        #pragma unroll
        for (int step = 0; step < 5; ++step) {
            const int half = 16 >> step;
            const int mask = 1 << step;
            const bool hi_lane = (lane & mask) != 0;
            #pragma unroll
            for (int i = 0; i < 16; ++i) {
                if (i >= half) break;
                const float lo = p[i], hi = p[i + half];
                const float send = hi_lane ? lo : hi;
                const float recv = __shfl_xor(send, mask);
                p[i] = (hi_lane ? hi : lo) + recv;
            }
        }
        const float sc = p[0] + __shfl_xor(p[0], 32);   // lane L: score_{L&31}

        // phase 2: softmax over k (scores are O(1); no max-subtract needed)
        const float ex = __expf(sc);
        float tt = ex;
        #pragma unroll
        for (int m2 = 1; m2 < 32; m2 <<= 1) tt += __shfl_xor(tt, m2);
        const float attL = ex * __builtin_amdgcn_rcpf(tt);

        // phase 3: aggregate from the saved N halves; att as scalar operand
        float nh0 = 0.0f, nh1 = 0.0f;
        #pragma unroll
        for (int k = 0; k < KNB; ++k) {
            const float a = __uint_as_float(
                __builtin_amdgcn_readlane(__float_as_uint(attL), k));
            const float2 t = __half22float2(u2h(nds[k]));
            nh0 = fmaf(a, t.x, nh0);
            nh1 = fmaf(a, t.y, nh1);
        }

        // store U/V row to swizzled LDS (chunk = 16B unit; chunk ^= row&7)
        const int chunk = lane >> 2;
        const int boff = r * 256 + ((chunk ^ (r & 7)) << 4) + (lane & 3) * 4;
        *(__half2*)((char*)Us + boff) = __floats2half2_rn(h.x + nh0, h.y + nh1);
        *(__half2*)((char*)Vs + boff) = __floats2half2_rn(h.x * nh0, h.y * nh1);
    }

    __syncthreads();

    // GEMM phase: waves 0..7, one coltile each; A-frags from swizzled LDS
    if (wid < 8) {
        const int m = lane & 15, quad = lane >> 4;
        f16x8 au[4], av[4];
        #pragma unroll
        for (int kt = 0; kt < 4; ++kt) {
            const int off = m * 256 + (((kt * 4 + quad) ^ (m & 7)) << 4);
            au[kt] = *(const f16x8*)((const char*)Us + off);
            av[kt] = *(const f16x8*)((const char*)Vs + off);
        }

        const int ct = wid;
        floatx4 accU = {0.0f, 0.0f, 0.0f, 0.0f};
        floatx4 accV = {0.0f, 0.0f, 0.0f, 0.0f};
        #pragma unroll
        for (int kt = 0; kt < 4; ++kt) {
            const f16x8 bu = *(const f16x8*)(W1h + (size_t)(ct * 16 + m) * DIM + kt * 32 + quad * 8);
            const f16x8 bv = *(const f16x8*)(W2h + (size_t)(ct * 16 + m) * DIM + kt * 32 + quad * 8);
            accU = __builtin_amdgcn_mfma_f32_16x16x32_f16(au[kt], bu, accU, 0, 0, 0);
            accV = __builtin_amdgcn_mfma_f32_16x16x32_f16(av[kt], bv, accV, 0, 0, 0);
        }
        const float bb1 = b1[ct * 16 + m];
        const float bb2 = b2[ct * 16 + m];
        #pragma unroll
        for (int r = 0; r < 4; ++r) {
            const float x = accU[r] + bb1;
            const float y = accV[r] + bb2;
            const float lx = x > 0.0f ? x : 0.2f * x;
            const float ly = y > 0.0f ? y : 0.2f * y;
            out[(size_t)(row0 + quad * 4 + r) * DIM + ct * 16 + m] = lx + ly;
        }
    }
}

extern "C" void kernel_launch(void* const* d_in, const int* in_sizes, int n_in,
                              void* d_out, int out_size, void* d_ws, size_t ws_size,
                              hipStream_t stream) {
    (void)in_sizes; (void)n_in; (void)out_size; (void)ws_size;
    const int*   idx     = (const int*)d_in[0];
    const int*   adj_ent = (const int*)d_in[1];
    const int*   adj_rel = (const int*)d_in[2];
    const float* ent     = (const float*)d_in[3];
    const float* rel     = (const float*)d_in[4];
    const float* Wr_w    = (const float*)d_in[5];
    const float* Wr_b    = (const float*)d_in[6];
    const float* W1_w    = (const float*)d_in[7];
    const float* W1_b    = (const float*)d_in[8];
    const float* W2_w    = (const float*)d_in[9];
    const float* W2_b    = (const float*)d_in[10];
    float* out = (float*)d_out;

    char* ws = (char*)d_ws;
    // workspace layout (bytes):
    char* NT    = ws;                              // 51,200,000 (100000 x 512)
    f16* REL16  = (f16*)(ws + 51200000);           //     16,384
    f16* Wr16   = (f16*)(ws + 51216384);           //     32,768
    f16* W116   = (f16*)(ws + 51249152);           //     32,768
    f16* W216   = (f16*)(ws + 51281920);           //     32,768  (total 51,314,688)

    k_small<<<dim3(80), dim3(256), 0, stream>>>(Wr_w, W1_w, W2_w, Wr16, W116, W216,
                                                rel, (__half2*)REL16);
    // 2 strips/wave, 8 strips/block -> ceil(6250/8) = 782 blocks
    k_pre<<<dim3((STRIPS + 7) / 8), dim3(256), 0, stream>>>(ent, Wr16, Wr_b, NT);
    // merged SA + output GEMM: one block per 16 batch rows, 16 waves/block
    k_sag<<<dim3(BATCH / 16), dim3(1024), 0, stream>>>(idx, adj_ent, adj_rel,
                                                       NT, (const __half2*)REL16,
                                                       W116, W1_b, W216, W2_b,
                                                       out);
}

// Round 9
// 176.879 us; speedup vs baseline: 1.3943x; 1.3943x over previous
//
#include <hip/hip_runtime.h>
#include <hip/hip_fp16.h>
#include <math.h>

#define N_ENT 100000
#define N_REL 64
#define DIM   128
#define KNB   32
#define BATCH 16384
#define STRIPS (N_ENT / 16)   // 6250

typedef _Float16 f16;
typedef __attribute__((ext_vector_type(2))) _Float16 f16x2;
typedef __attribute__((ext_vector_type(8))) _Float16 f16x8;
typedef __attribute__((ext_vector_type(4))) float floatx4;

__device__ __forceinline__ int clamp_id(int id) {
    return id < 0 ? 0 : (id > N_ENT - 1 ? N_ENT - 1 : id);
}

__device__ __forceinline__ f16x2 h2v(__half2 h) {
    union { __half2 h; f16x2 v; } u; u.h = h; return u.v;
}

// ---------------------------------------------------------------------------
// Kernel S (merged small prep):
//  blocks 0..63:  f16 copies of Wr/W1/W2 (row-major = MFMA B layout)
//  blocks 64..79: REL16 = f16(maxnorm(rel_table)), one wave per row
// ---------------------------------------------------------------------------
__global__ __launch_bounds__(256) void k_small(
    const float* __restrict__ Wr, const float* __restrict__ W1,
    const float* __restrict__ W2, f16* __restrict__ Wr16,
    f16* __restrict__ W116, f16* __restrict__ W216,
    const float* __restrict__ rel, __half2* __restrict__ REL2)
{
    if (blockIdx.x < 64) {
        const int t = blockIdx.x * 256 + threadIdx.x;   // 0..16383
        Wr16[t] = (f16)Wr[t];
        W116[t] = (f16)W1[t];
        W216[t] = (f16)W2[t];
    } else {
        const int lane = threadIdx.x & 63;
        const int row  = (blockIdx.x - 64) * 4 + (threadIdx.x >> 6);
        const float2 x = *(const float2*)(rel + row * DIM + 2 * lane);
        float ss = x.x * x.x + x.y * x.y;
        #pragma unroll
        for (int m = 1; m < 64; m <<= 1) ss += __shfl_xor(ss, m);
        const float s = fminf(1.0f, 1.0f / fmaxf(sqrtf(ss), 1e-12f));
        REL2[row * 64 + lane] = __floats2half2_rn(x.x * s, x.y * s);
    }
}

// ---------------------------------------------------------------------------
// Kernel P v2 (R5 version): fused maxnorm + GEMM, separate N16/TR16 tables.
//  - Wr staged to LDS once per block in MFMA-fragment order (conflict-free
//    ds_read_b128); kills the serialized global b-loads (v1: 44us latency).
//  - 2 strips per wave; 16 ent loads issued up-front.
// (R7's interleaved-NT variant is reverted: it forced k_sag to keep 32
//  gathered values live across the reduce tree -> 250MB scratch spill.)
// ---------------------------------------------------------------------------
__global__ __launch_bounds__(256, 4) void k_pre(
    const float* __restrict__ ent, const f16* __restrict__ B,
    const float* __restrict__ bias, f16* __restrict__ TR16,
    f16* __restrict__ N16)
{
    __shared__ f16 Bs[32 * 512];   // 32 slots x 1024B = 32 KB
    const int wid  = threadIdx.x >> 6;
    const int lane = threadIdx.x & 63;
    const int m = lane & 15, quad = lane >> 4;

    // stage B into LDS in fragment order (8 slots per wave)
    #pragma unroll
    for (int i = 0; i < 8; ++i) {
        const int s  = wid * 8 + i;
        const int ct = s >> 2, kt = s & 3;
        const f16* gsrc = B + (size_t)(ct * 16 + m) * DIM + kt * 32 + quad * 8;
        __builtin_amdgcn_global_load_lds(
            (const __attribute__((address_space(1))) unsigned int*)gsrc,
            (__attribute__((address_space(3))) unsigned int*)(Bs + s * 512),
            16, 0, 0);
    }

    // two strips per wave; clamp => redundant but bitwise-identical writes
    const int wstrip = (blockIdx.x * 4 + wid) * 2;
    const int s0 = wstrip     < STRIPS ? wstrip     : STRIPS - 1;
    const int s1 = wstrip + 1 < STRIPS ? wstrip + 1 : STRIPS - 1;

    const float* __restrict__ src0 = ent + (size_t)(s0 * 16 + m) * DIM + quad * 8;
    const float* __restrict__ src1 = ent + (size_t)(s1 * 16 + m) * DIM + quad * 8;
    float x0[4][8], x1[4][8];
    #pragma unroll
    for (int kt = 0; kt < 4; ++kt) {
        *(float4*)&x0[kt][0] = *(const float4*)(src0 + kt * 32);
        *(float4*)&x0[kt][4] = *(const float4*)(src0 + kt * 32 + 4);
    }
    #pragma unroll
    for (int kt = 0; kt < 4; ++kt) {
        *(float4*)&x1[kt][0] = *(const float4*)(src1 + kt * 32);
        *(float4*)&x1[kt][4] = *(const float4*)(src1 + kt * 32 + 4);
    }
    __builtin_amdgcn_sched_barrier(0);   // all 16 loads + staging stay issued here

    // strip 0: norm -> a-frags -> N16
    float ss0 = 0.0f;
    #pragma unroll
    for (int kt = 0; kt < 4; ++kt)
        #pragma unroll
        for (int j = 0; j < 8; ++j) ss0 = fmaf(x0[kt][j], x0[kt][j], ss0);
    ss0 += __shfl_xor(ss0, 16);
    ss0 += __shfl_xor(ss0, 32);
    const float sc0 = fminf(1.0f, 1.0f / fmaxf(sqrtf(ss0), 1e-12f));
    f16x8 a0[4];
    {
        f16* __restrict__ ndst = N16 + (size_t)(s0 * 16 + m) * DIM + quad * 8;
        #pragma unroll
        for (int kt = 0; kt < 4; ++kt) {
            f16x8 av;
            #pragma unroll
            for (int j = 0; j < 8; ++j) av[j] = (f16)(x0[kt][j] * sc0);
            a0[kt] = av;
            *(f16x8*)(ndst + kt * 32) = av;
        }
    }

    // strip 1
    float ss1 = 0.0f;
    #pragma unroll
    for (int kt = 0; kt < 4; ++kt)
        #pragma unroll
        for (int j = 0; j < 8; ++j) ss1 = fmaf(x1[kt][j], x1[kt][j], ss1);
    ss1 += __shfl_xor(ss1, 16);
    ss1 += __shfl_xor(ss1, 32);
    const float sc1 = fminf(1.0f, 1.0f / fmaxf(sqrtf(ss1), 1e-12f));
    f16x8 a1[4];
    {
        f16* __restrict__ ndst = N16 + (size_t)(s1 * 16 + m) * DIM + quad * 8;
        #pragma unroll
        for (int kt = 0; kt < 4; ++kt) {
            f16x8 av;
            #pragma unroll
            for (int j = 0; j < 8; ++j) av[j] = (f16)(x1[kt][j] * sc1);
            a1[kt] = av;
            *(f16x8*)(ndst + kt * 32) = av;
        }
    }

    __syncthreads();   // staging complete (drains vmcnt), LDS visible

    // MFMA: 8 col-tiles x 4 k-tiles; b from LDS feeds both strips
    #pragma unroll
    for (int ct = 0; ct < 8; ++ct) {
        floatx4 acc0 = {0.0f, 0.0f, 0.0f, 0.0f};
        floatx4 acc1 = {0.0f, 0.0f, 0.0f, 0.0f};
        #pragma unroll
        for (int kt = 0; kt < 4; ++kt) {
            const f16x8 b = *(const f16x8*)(Bs + (ct * 4 + kt) * 512 + lane * 8);
            acc0 = __builtin_amdgcn_mfma_f32_16x16x32_f16(a0[kt], b, acc0, 0, 0, 0);
            acc1 = __builtin_amdgcn_mfma_f32_16x16x32_f16(a1[kt], b, acc1, 0, 0, 0);
        }
        const float bb = bias[ct * 16 + m];
        #pragma unroll
        for (int r = 0; r < 4; ++r) {
            TR16[(size_t)(s0 * 16 + quad * 4 + r) * DIM + ct * 16 + m] = (f16)(acc0[r] + bb);
            TR16[(size_t)(s1 * 16 + quad * 4 + r) * DIM + ct * 16 + m] = (f16)(acc1[r] + bb);
        }
    }
}

// ---------------------------------------------------------------------------
// Kernel SG v5 = R5 structure (best measured: 45.6us) + REL-in-LDS.
// One block = 16 batch rows, 16 waves (1024 threads), one element per wave.
// NEW vs R5: the 16KB REL table is staged to LDS once per block
// (global_load_lds, linear both sides) and phase 1 reads rn2 via ds_read.
// Removes 32 of ~100 VMEM instructions/wave from the vmcnt queue (REL moves
// to the lgkm counter and overlaps the TR/N gathers). Zero numerics change,
// zero register-pressure change (tnd loads stay compiler-sunk to phase 3 --
// R7 proved forcing them live spills 250MB of scratch).
// ---------------------------------------------------------------------------
__global__ __launch_bounds__(1024, 8) void k_sag(
    const int* __restrict__ idx, const int* __restrict__ adj_ent,
    const int* __restrict__ adj_rel, const __half2* __restrict__ TR2,
    const __half2* __restrict__ N2, const __half2* __restrict__ REL2,
    const f16* __restrict__ W1h, const float* __restrict__ b1,
    const f16* __restrict__ W2h, const float* __restrict__ b2,
    float* __restrict__ out)
{
    __shared__ __half2 Rs[64 * 64];  // 16 KB staged REL table
    __shared__ f16 Us[16 * DIM];     // 4 KB, 16B-chunk XOR swizzle by row
    __shared__ f16 Vs[16 * DIM];     // 4 KB
    const int wid  = threadIdx.x >> 6;   // 0..15 = element / LDS row
    const int lane = threadIdx.x & 63;
    const int row0 = blockIdx.x * 16;

    // stage REL: 16 waves x 1KB, linear src and dst
    __builtin_amdgcn_global_load_lds(
        (const __attribute__((address_space(1))) unsigned int*)(REL2 + wid * 256 + lane * 4),
        (__attribute__((address_space(3))) unsigned int*)(Rs + wid * 256 + lane * 4),
        16, 0, 0);

    const __half2 C1 = __float2half2_rn(-0.33333334f);
    const __half2 C2 = __float2half2_rn(0.13333334f);

    const int r = wid;
    const int b = row0 + r;
    const int id = clamp_id(idx[b]);
    const __half2 hr2 = TR2[(size_t)id * 64 + lane];   // keep packed
    const float2 h  = __half22float2(N2[(size_t)id * 64 + lane]);
    const int eL = adj_ent[(size_t)id * KNB + (lane & 31)];
    const int rL = adj_rel[(size_t)id * KNB + (lane & 31)];

    __syncthreads();   // Rs ready (drains the staging vmcnt)

    {
        // prefetch phase-3 rows (compiler sinks these to phase 3 -- keep it so)
        unsigned int tnd[KNB];
        #pragma unroll
        for (int k = 0; k < KNB; ++k) {
            const int e = __builtin_amdgcn_readlane(eL, k);
            tnd[k] = *((const unsigned int*)N2 + (size_t)e * 64 + lane);
        }

        // phase 1: independent partials p[k], packed f16 tanh + fdot2
        float p[KNB];
        #pragma unroll
        for (int k = 0; k < KNB; ++k) {
            const int e  = __builtin_amdgcn_readlane(eL, k);
            const int rr = __builtin_amdgcn_readlane(rL, k);
            const __half2 tr2 = TR2[(size_t)e * 64 + lane];
            const __half2 rn2 = Rs[rr * 64 + lane];
            const __half2 x  = __hadd2(hr2, rn2);
            const __half2 xx = __hmul2(x, x);
            __half2 q = __hfma2(xx, C2, C1);     // c1 + c2*x2
            q = __hmul2(q, xx);                  // x2*(c1 + c2*x2)
            const __half2 mm = __hfma2(x, q, x); // tanh(x) approx
#if __has_builtin(__builtin_amdgcn_fdot2)
            p[k] = __builtin_amdgcn_fdot2(h2v(mm), h2v(tr2), 0.0f, false);
#else
            const float2 mf = __half22float2(mm);
            const float2 tf = __half22float2(tr2);
            p[k] = mf.x * tf.x + mf.y * tf.y;
#endif
        }

        // transpose-reduce tree: all 32 lane-sums at once
        #pragma unroll
        for (int step = 0; step < 5; ++step) {
            const int half = 16 >> step;
            const int mask = 1 << step;
            const bool hi_lane = (lane & mask) != 0;
            #pragma unroll
            for (int i = 0; i < 16; ++i) {
                if (i >= half) break;
                const float lo = p[i], hi = p[i + half];
                const float send = hi_lane ? lo : hi;
                const float recv = __shfl_xor(send, mask);
                p[i] = (hi_lane ? hi : lo) + recv;
            }
        }
        const float sc = p[0] + __shfl_xor(p[0], 32);   // lane L: score_{L&31}

        // phase 2: softmax over k (scores are O(1); no max-subtract needed)
        const float ex = __expf(sc);
        float tt = ex;
        #pragma unroll
        for (int m2 = 1; m2 < 32; m2 <<= 1) tt += __shfl_xor(tt, m2);
        const float attL = ex * __builtin_amdgcn_rcpf(tt);

        // phase 3: aggregate; att as scalar operand
        float nh0 = 0.0f, nh1 = 0.0f;
        #pragma unroll
        for (int k = 0; k < KNB; ++k) {
            const float a = __uint_as_float(
                __builtin_amdgcn_readlane(__float_as_uint(attL), k));
            const float2 t = __half22float2(*(const __half2*)&tnd[k]);
            nh0 = fmaf(a, t.x, nh0);
            nh1 = fmaf(a, t.y, nh1);
        }

        // store U/V row to swizzled LDS (chunk = 16B unit; chunk ^= row&7)
        const int chunk = lane >> 2;
        const int boff = r * 256 + ((chunk ^ (r & 7)) << 4) + (lane & 3) * 4;
        *(__half2*)((char*)Us + boff) = __floats2half2_rn(h.x + nh0, h.y + nh1);
        *(__half2*)((char*)Vs + boff) = __floats2half2_rn(h.x * nh0, h.y * nh1);
    }

    __syncthreads();

    // GEMM phase: waves 0..7, one coltile each; A-frags from swizzled LDS
    if (wid < 8) {
        const int m = lane & 15, quad = lane >> 4;
        f16x8 au[4], av[4];
        #pragma unroll
        for (int kt = 0; kt < 4; ++kt) {
            const int off = m * 256 + (((kt * 4 + quad) ^ (m & 7)) << 4);
            au[kt] = *(const f16x8*)((const char*)Us + off);
            av[kt] = *(const f16x8*)((const char*)Vs + off);
        }

        const int ct = wid;
        floatx4 accU = {0.0f, 0.0f, 0.0f, 0.0f};
        floatx4 accV = {0.0f, 0.0f, 0.0f, 0.0f};
        #pragma unroll
        for (int kt = 0; kt < 4; ++kt) {
            const f16x8 bu = *(const f16x8*)(W1h + (size_t)(ct * 16 + m) * DIM + kt * 32 + quad * 8);
            const f16x8 bv = *(const f16x8*)(W2h + (size_t)(ct * 16 + m) * DIM + kt * 32 + quad * 8);
            accU = __builtin_amdgcn_mfma_f32_16x16x32_f16(au[kt], bu, accU, 0, 0, 0);
            accV = __builtin_amdgcn_mfma_f32_16x16x32_f16(av[kt], bv, accV, 0, 0, 0);
        }
        const float bb1 = b1[ct * 16 + m];
        const float bb2 = b2[ct * 16 + m];
        #pragma unroll
        for (int r2 = 0; r2 < 4; ++r2) {
            const float x = accU[r2] + bb1;
            const float y = accV[r2] + bb2;
            const float lx = x > 0.0f ? x : 0.2f * x;
            const float ly = y > 0.0f ? y : 0.2f * y;
            out[(size_t)(row0 + quad * 4 + r2) * DIM + ct * 16 + m] = lx + ly;
        }
    }
}

extern "C" void kernel_launch(void* const* d_in, const int* in_sizes, int n_in,
                              void* d_out, int out_size, void* d_ws, size_t ws_size,
                              hipStream_t stream) {
    (void)in_sizes; (void)n_in; (void)out_size; (void)ws_size;
    const int*   idx     = (const int*)d_in[0];
    const int*   adj_ent = (const int*)d_in[1];
    const int*   adj_rel = (const int*)d_in[2];
    const float* ent     = (const float*)d_in[3];
    const float* rel     = (const float*)d_in[4];
    const float* Wr_w    = (const float*)d_in[5];
    const float* Wr_b    = (const float*)d_in[6];
    const float* W1_w    = (const float*)d_in[7];
    const float* W1_b    = (const float*)d_in[8];
    const float* W2_w    = (const float*)d_in[9];
    const float* W2_b    = (const float*)d_in[10];
    float* out = (float*)d_out;

    char* ws = (char*)d_ws;
    // workspace layout (bytes):
    f16* N16   = (f16*)(ws);                       // 25,600,000
    f16* TR16  = (f16*)(ws + 25600000);            // 25,600,000
    f16* REL16 = (f16*)(ws + 51200000);            //     16,384
    f16* Wr16  = (f16*)(ws + 59604992);            //     32,768
    f16* W116  = (f16*)(ws + 59637760);            //     32,768
    f16* W216  = (f16*)(ws + 59670528);            //     32,768  (total 59,703,296)

    k_small<<<dim3(80), dim3(256), 0, stream>>>(Wr_w, W1_w, W2_w, Wr16, W116, W216,
                                                rel, (__half2*)REL16);
    // 2 strips/wave, 8 strips/block -> ceil(6250/8) = 782 blocks
    k_pre<<<dim3((STRIPS + 7) / 8), dim3(256), 0, stream>>>(ent, Wr16, Wr_b,
                                                            TR16, N16);
    // merged SA + output GEMM: one block per 16 batch rows, 16 waves/block
    k_sag<<<dim3(BATCH / 16), dim3(1024), 0, stream>>>(idx, adj_ent, adj_rel,
                                                       (const __half2*)TR16,
                                                       (const __half2*)N16,
                                                       (const __half2*)REL16,
                                                       W116, W1_b, W216, W2_b,
                                                       out);
}